// Round 2
// baseline (118.365 us; speedup 1.0000x reference)
//
#include <hip/hip_runtime.h>
#include <math.h>

// ---------------------------------------------------------------------------
// ConvQCL: quanvolutional net.
//   conv cells: 9-qubit REAL state (512 floats) in LDS, 1 block/cell.
//   dense cells: 16-qubit complex state (64K amps) in d_ws global memory.
//     CNOT staircase == Gray-code basis permutation: amp'(c) = amp(c ^ (c>>1)).
//     Layer = perm + 16 single-wire RYs, split into:
//       passA: wires 3..15 (low 13 bits) in 64KB LDS slabs, in-place
//       passB: wires 0..2 (top 3 bits) in registers; scatter through next
//              staircase's inverse-Gray map (ping-pong), or fuse measurement.
// ws requirement: ~34 MB (2 x 16MB state ping-pong + small buffers).
// ---------------------------------------------------------------------------

__device__ __forceinline__ unsigned ginv16(unsigned b) {
    // inverse of g(c)=c^(c>>1): prefix-XOR from MSB
    b ^= b >> 1; b ^= b >> 2; b ^= b >> 4; b ^= b >> 8;
    return b & 0xFFFFu;
}

__device__ __forceinline__ float2 cmul(float2 a, float2 b) {
    return make_float2(a.x * b.x - a.y * b.y, a.x * b.y + a.y * b.x);
}

// ---------------- K1: conv cells ----------------
// grid: B*64 blocks, 256 threads. cv[cell] = <Z_0> of the 9-qubit circuit.
__global__ void __launch_bounds__(256)
k_conv(const float* __restrict__ x, const float* __restrict__ wc,
       float* __restrict__ cv, int cdepth)
{
    __shared__ float st[512];
    __shared__ float c9[9], s9[9];
    __shared__ float cg[8][9], sg[8][9];   // supports cdepth <= 8

    const int tid  = threadIdx.x;
    const int cell = blockIdx.x;
    const int b = cell >> 6, pos = cell & 63, r = pos >> 3, c = pos & 7;

    if (tid < 9) {
        int kh = tid / 3, kw = tid % 3;
        int rr = r - 1 + kh, cc = c - 1 + kw;
        float ang = 0.f;                       // zero padding -> angle 0
        if (rr >= 0 && rr < 8 && cc >= 0 && cc < 8) {
            float v = x[(b * 8 + rr) * 8 + cc];
            ang = asinf(2.f * v - 1.f);        // xa = arcsin(2(x-0.5))
        }
        float sv, cvv; sincosf(0.5f * ang, &sv, &cvv);
        c9[tid] = cvv; s9[tid] = sv;
    }
    if (tid < 9 * cdepth) {
        int k = tid / 9, i = tid % 9;
        float sv, cvv; sincosf(0.5f * wc[k * 9 + i], &sv, &cvv);
        cg[k][i] = cvv; sg[k][i] = sv;
    }
    __syncthreads();

    // initial product state: amp(idx) = prod_w (bit? sin : cos), wire w = bit (8-w)
    #pragma unroll
    for (int rep = 0; rep < 2; ++rep) {
        int idx = tid + rep * 256;
        float a = 1.f;
        #pragma unroll
        for (int w = 0; w < 9; ++w) {
            int bit = (idx >> (8 - w)) & 1;
            a *= bit ? s9[w] : c9[w];
        }
        st[idx] = a;
    }
    __syncthreads();

    for (int k = 0; k < cdepth; ++k) {
        // CNOT staircase: control wire i (bit 8-i), target wire i+1 (bit 7-i)
        for (int i = 0; i < 8; ++i) {
            if (tid < 128) {
                int pt = 7 - i;                       // target bit position
                int low  = tid & ((1 << pt) - 1);
                int high = tid >> pt;
                int base = (high << (pt + 2)) | low;  // bits pt, pt+1 clear
                int i0 = base | (1 << (pt + 1));      // control bit = 1
                int i1 = i0 | (1 << pt);
                float t0 = st[i0]; st[i0] = st[i1]; st[i1] = t0;
            }
            __syncthreads();
        }
        // RY layer
        for (int w = 0; w < 9; ++w) {
            int p = 8 - w;
            int low  = tid & ((1 << p) - 1);
            int high = tid >> p;
            int i0 = (high << (p + 1)) | low;
            int i1 = i0 | (1 << p);
            float a0 = st[i0], a1 = st[i1];
            float cc = cg[k][w], ss = sg[k][w];
            st[i0] = cc * a0 - ss * a1;
            st[i1] = ss * a0 + cc * a1;
            __syncthreads();
        }
    }

    // <Z0> = sum_{idx<256} a^2 - sum_{idx>=256} a^2
    float v = st[tid] * st[tid] - st[tid + 256] * st[tid + 256];
    __syncthreads();
    st[tid] = v;
    __syncthreads();
    for (int off = 128; off > 0; off >>= 1) {
        if (tid < off) st[tid] += st[tid + off];
        __syncthreads();
    }
    if (tid == 0) cv[cell] = st[0];
}

// ---------------- K2: maxpool + dense init (with staircase-1 perm applied) ----
// grid: B blocks, 256 threads.
__global__ void __launch_bounds__(256)
k_dense_init(const float* __restrict__ cv, float2* __restrict__ buf0)
{
    __shared__ float2 coef[16][2];
    __shared__ float2 TH[256], TL[256];
    const int tid  = threadIdx.x;
    const int cell = blockIdx.x;

    if (tid < 16) {
        int pr = tid >> 2, pc = tid & 3;
        const float* base = cv + cell * 64;
        float m0 = base[(2 * pr) * 8 + 2 * pc];
        float m1 = base[(2 * pr) * 8 + 2 * pc + 1];
        float m2 = base[(2 * pr + 1) * 8 + 2 * pc];
        float m3 = base[(2 * pr + 1) * 8 + 2 * pc + 1];
        float xv = fmaxf(fmaxf(m0, m1), fmaxf(m2, m3));
        xv = fminf(1.f, fmaxf(-1.f, xv));      // guard asin domain vs fp error
        float a  = asinf(xv);
        float bb = acosf(xv * xv);
        float sa, ca, sb, cb2;
        sincosf(0.5f * a,  &sa, &ca);
        sincosf(0.5f * bb, &sb, &cb2);
        // RZ(b) RY(a) |0> : [e^{-ib/2} cos(a/2), e^{+ib/2} sin(a/2)]
        coef[tid][0] = make_float2(cb2 * ca, -sb * ca);
        coef[tid][1] = make_float2(cb2 * sa,  sb * sa);
    }
    __syncthreads();

    // factored product tables: TH over wires 0..7 (bits 15..8), TL wires 8..15
    float2 ph = make_float2(1.f, 0.f), pl = make_float2(1.f, 0.f);
    #pragma unroll
    for (int i = 0; i < 8; ++i) {
        int bit = (tid >> (7 - i)) & 1;
        ph = cmul(ph, coef[i][bit]);
        pl = cmul(pl, coef[8 + i][bit]);
    }
    TH[tid] = ph; TL[tid] = pl;
    __syncthreads();

    float2* out = buf0 + (size_t)cell * 65536;
    for (int it = 0; it < 256; ++it) {
        unsigned cidx = (unsigned)(it * 256 + tid);
        unsigned bidx = cidx ^ (cidx >> 1);              // gather through perm
        out[cidx] = cmul(TH[bidx >> 8], TL[bidx & 255]);
    }
}

// ---------------- K3: pass A — RY wires 3..15 in 8192-amp LDS slabs, in-place
// grid: B*8 blocks, 256 threads.
__global__ void __launch_bounds__(256)
k_passA(float2* __restrict__ buf, const float* __restrict__ wd, int k)
{
    __shared__ float2 tile[8192];   // 64 KB
    const int tid = threadIdx.x;
    float2* g = buf + (size_t)blockIdx.x * 8192;

    for (int it = 0; it < 32; ++it)
        tile[it * 256 + tid] = g[it * 256 + tid];
    __syncthreads();

    for (int w = 3; w < 16; ++w) {
        int p = 15 - w;                          // bit position 12..0
        float sv, cvv; sincosf(0.5f * wd[k * 16 + w], &sv, &cvv);
        for (int q = 0; q < 16; ++q) {
            int pi   = q * 256 + tid;            // pair index 0..4095
            int low  = pi & ((1 << p) - 1);
            int high = pi >> p;
            int i0 = (high << (p + 1)) | low;
            int i1 = i0 | (1 << p);
            float2 a0 = tile[i0], a1 = tile[i1];
            tile[i0] = make_float2(cvv * a0.x - sv * a1.x, cvv * a0.y - sv * a1.y);
            tile[i1] = make_float2(sv * a0.x + cvv * a1.x, sv * a0.y + cvv * a1.y);
        }
        __syncthreads();
    }

    for (int it = 0; it < 32; ++it)
        g[it * 256 + tid] = tile[it * 256 + tid];
}

// helper shared by passB kernels: load 8 strided amps + apply RY wires 0..2
__device__ __forceinline__ void passB_core(const float2* __restrict__ gi,
                                           unsigned low13,
                                           const float* __restrict__ wd, int k,
                                           float2 v[8])
{
    #pragma unroll
    for (int j = 0; j < 8; ++j) v[j] = gi[(j << 13) | low13];
    #pragma unroll
    for (int w = 0; w < 3; ++w) {
        float sv, cvv; sincosf(0.5f * wd[k * 16 + w], &sv, &cvv);
        const int stride = 1 << (2 - w);         // wire0 -> j bit2
        #pragma unroll
        for (int j = 0; j < 8; ++j) {
            if (!(j & stride)) {
                float2 a0 = v[j], a1 = v[j | stride];
                v[j]          = make_float2(cvv * a0.x - sv * a1.x,
                                            cvv * a0.y - sv * a1.y);
                v[j | stride] = make_float2(sv * a0.x + cvv * a1.x,
                                            sv * a0.y + cvv * a1.y);
            }
        }
    }
}

// ---------------- K4: pass B + scatter through next staircase perm ----------
// grid: B*32 blocks, 256 threads; 8 amps/thread.
__global__ void __launch_bounds__(256)
k_passB_perm(const float2* __restrict__ in, float2* __restrict__ outb,
             const float* __restrict__ wd, int k)
{
    const int tid   = threadIdx.x;
    const int cell  = blockIdx.x >> 5;
    const int chunk = blockIdx.x & 31;
    const unsigned low13 = (unsigned)(chunk * 256 + tid);
    const float2* gi = in   + (size_t)cell * 65536;
    float2*       go = outb + (size_t)cell * 65536;

    float2 v[8];
    passB_core(gi, low13, wd, k, v);

    #pragma unroll
    for (int j = 0; j < 8; ++j) {
        unsigned bidx = ((unsigned)j << 13) | low13;
        go[ginv16(bidx)] = v[j];                 // amp lands where next perm reads it
    }
}

// ---------------- K5: final pass B + measurement ----------------------------
// grid: B*32 blocks, 256 threads. partial[block][i] = sum of P contributions
// with wire-i bit == 0 over this block's 2048 amps. Deterministic (no atomics).
__global__ void __launch_bounds__(256)
k_passB_measure(const float2* __restrict__ in, const float* __restrict__ wd,
                int k, float* __restrict__ partial)
{
    __shared__ float red[256][17];
    const int tid   = threadIdx.x;
    const int cell  = blockIdx.x >> 5;
    const int chunk = blockIdx.x & 31;
    const unsigned low13 = (unsigned)(chunk * 256 + tid);
    const float2* gi = in + (size_t)cell * 65536;

    float2 v[8];
    passB_core(gi, low13, wd, k, v);

    float p[8];
    #pragma unroll
    for (int j = 0; j < 8; ++j) p[j] = v[j].x * v[j].x + v[j].y * v[j].y;

    float sum8 = p[0] + p[1] + p[2] + p[3] + p[4] + p[5] + p[6] + p[7];
    float ws16[16];
    ws16[0] = p[0] + p[1] + p[2] + p[3];   // wire0 (j bit2 == 0)
    ws16[1] = p[0] + p[1] + p[4] + p[5];   // wire1 (j bit1 == 0)
    ws16[2] = p[0] + p[2] + p[4] + p[6];   // wire2 (j bit0 == 0)
    #pragma unroll
    for (int w = 3; w < 16; ++w) {
        int bit = (int)(low13 >> (15 - w)) & 1;
        ws16[w] = bit ? 0.f : sum8;
    }

    #pragma unroll
    for (int i = 0; i < 16; ++i) red[tid][i] = ws16[i];
    __syncthreads();
    if (tid < 16) {
        float t = 0.f;
        for (int j = 0; j < 256; ++j) t += red[j][tid];
        partial[(size_t)blockIdx.x * 16 + tid] = t;
    }
}

// ---------------- K6: feats @ w_out + b_out ---------------------------------
__global__ void k_out(const float* __restrict__ partial,
                      const float* __restrict__ w_out,
                      const float* __restrict__ b_out,
                      float* __restrict__ out, int B, int odim)
{
    int t = blockIdx.x * blockDim.x + threadIdx.x;
    if (t >= B * odim) return;
    int b = t / odim, o = t % odim;
    float acc = b_out[o];
    for (int i = 0; i < 16; ++i) {
        float f = 0.f;
        const float* pp = partial + (size_t)(b * 32) * 16 + i;
        for (int c2 = 0; c2 < 32; ++c2) f += pp[c2 * 16];
        acc += f * w_out[i * odim + o];
    }
    out[t] = acc;
}

// ---------------------------------------------------------------------------
extern "C" void kernel_launch(void* const* d_in, const int* in_sizes, int n_in,
                              void* d_out, int out_size, void* d_ws, size_t ws_size,
                              hipStream_t stream)
{
    (void)n_in; (void)out_size; (void)ws_size;
    const float* x     = (const float*)d_in[0];
    const float* wc    = (const float*)d_in[1];
    const float* wd    = (const float*)d_in[2];
    const float* w_out = (const float*)d_in[3];
    const float* b_out = (const float*)d_in[4];
    float* out = (float*)d_out;

    const int B      = in_sizes[0] / 64;    // 32
    const int cdepth = in_sizes[1] / 9;     // 2
    const int ddepth = in_sizes[2] / 16;    // 2
    const int odim   = in_sizes[3] / 16;    // 10

    char* ws = (char*)d_ws;
    size_t off = 0;
    float* cv = (float*)(ws + off);              off += (size_t)B * 64 * sizeof(float);
    off = (off + 255) & ~(size_t)255;
    float* partial = (float*)(ws + off);         off += (size_t)B * 32 * 16 * sizeof(float);
    off = (off + 255) & ~(size_t)255;
    float2* buf0 = (float2*)(ws + off);          off += (size_t)B * 65536 * sizeof(float2);
    float2* buf1 = (float2*)(ws + off);          // + B*65536*8 more

    k_conv<<<B * 64, 256, 0, stream>>>(x, wc, cv, cdepth);
    k_dense_init<<<B, 256, 0, stream>>>(cv, buf0);

    float2* cur = buf0;
    float2* oth = buf1;
    for (int k = 0; k < ddepth; ++k) {
        k_passA<<<B * 8, 256, 0, stream>>>(cur, wd, k);
        if (k < ddepth - 1) {
            k_passB_perm<<<B * 32, 256, 0, stream>>>(cur, oth, wd, k);
            float2* t = cur; cur = oth; oth = t;
        } else {
            k_passB_measure<<<B * 32, 256, 0, stream>>>(cur, wd, k, partial);
        }
    }

    int nt = B * odim;
    k_out<<<(nt + 255) / 256, 256, 0, stream>>>(partial, w_out, b_out, out, B, odim);
}

// Round 3
// 62.964 us; speedup vs baseline: 1.8799x; 1.8799x over previous
//
#include <hip/hip_runtime.h>
#include <math.h>

// ---------------------------------------------------------------------------
// ConvQCL — quanvolution + 16-qubit dense quantum circuit.
//
// Dense pipeline (ddepth=2 fast path, generic ddepth>=1 supported):
//   K_slab<INIT>:  psi0 gray-gathered (folds perm P0) + layer-0 RY on bits
//                  0..12 (wires 3..15), registers + 2 LDS transposes. write.
//   K_mid:         B0 high (wires 0..2) + perm P1 (3-bit gray gather +
//                  partner exchange tid^128) + B1 high.  read+write.
//   K_slab<MEAS>:  layer-1 RY on bits 0..12 + fused per-wire marginals. read.
// CNOT staircase == index map amp'(c) = amp(c ^ (c>>1)); its low-13 restriction
// maps slabs to slabs: L' = Ginv13(L ^ (h'_0<<12)).
// ---------------------------------------------------------------------------

__device__ __forceinline__ float2 cmul(float2 a, float2 b) {
    return make_float2(a.x * b.x - a.y * b.y, a.x * b.y + a.y * b.x);
}
__device__ __forceinline__ unsigned ginv13(unsigned x) {
    x ^= x >> 1; x ^= x >> 2; x ^= x >> 4; x ^= x >> 8;
    return x & 0x1FFFu;
}
// LDS XOR swizzle on float2 index (breaks stride-32 bank conflicts)
__device__ __forceinline__ int sw(int i) { return i ^ ((i >> 5) & 31); }

#define BFLY(A0, A1, C, S)                                        \
    {                                                             \
        float2 t0 = (A0), t1 = (A1);                              \
        (A0) = make_float2((C)*t0.x - (S)*t1.x, (C)*t0.y - (S)*t1.y); \
        (A1) = make_float2((S)*t0.x + (C)*t1.x, (S)*t0.y + (C)*t1.y); \
    }

// ---------------- K1: conv cells (9-qubit real state in LDS) ----------------
__global__ void __launch_bounds__(256)
k_conv(const float* __restrict__ x, const float* __restrict__ wc,
       float* __restrict__ cv, int cdepth)
{
    __shared__ float st[512];
    __shared__ float c9[9], s9[9];
    __shared__ float cg[8][9], sg[8][9];

    const int tid  = threadIdx.x;
    const int cell = blockIdx.x;
    const int b = cell >> 6, pos = cell & 63, r = pos >> 3, c = pos & 7;

    if (tid < 9) {
        int kh = tid / 3, kw = tid % 3;
        int rr = r - 1 + kh, cc = c - 1 + kw;
        float ang = 0.f;
        if (rr >= 0 && rr < 8 && cc >= 0 && cc < 8) {
            float v = x[(b * 8 + rr) * 8 + cc];
            ang = asinf(2.f * v - 1.f);
        }
        float sv, cvv; sincosf(0.5f * ang, &sv, &cvv);
        c9[tid] = cvv; s9[tid] = sv;
    }
    if (tid < 9 * cdepth) {
        int k = tid / 9, i = tid % 9;
        float sv, cvv; sincosf(0.5f * wc[k * 9 + i], &sv, &cvv);
        cg[k][i] = cvv; sg[k][i] = sv;
    }
    __syncthreads();

    #pragma unroll
    for (int rep = 0; rep < 2; ++rep) {
        int idx = tid + rep * 256;
        float a = 1.f;
        #pragma unroll
        for (int w = 0; w < 9; ++w) {
            int bit = (idx >> (8 - w)) & 1;
            a *= bit ? s9[w] : c9[w];
        }
        st[idx] = a;
    }
    __syncthreads();

    for (int k = 0; k < cdepth; ++k) {
        for (int i = 0; i < 8; ++i) {
            if (tid < 128) {
                int pt = 7 - i;
                int low  = tid & ((1 << pt) - 1);
                int high = tid >> pt;
                int base = (high << (pt + 2)) | low;
                int i0 = base | (1 << (pt + 1));
                int i1 = i0 | (1 << pt);
                float t0 = st[i0]; st[i0] = st[i1]; st[i1] = t0;
            }
            __syncthreads();
        }
        for (int w = 0; w < 9; ++w) {
            int p = 8 - w;
            int low  = tid & ((1 << p) - 1);
            int high = tid >> p;
            int i0 = (high << (p + 1)) | low;
            int i1 = i0 | (1 << p);
            float a0 = st[i0], a1 = st[i1];
            float cc = cg[k][w], ss = sg[k][w];
            st[i0] = cc * a0 - ss * a1;
            st[i1] = ss * a0 + cc * a1;
            __syncthreads();
        }
    }

    float v = st[tid] * st[tid] - st[tid + 256] * st[tid + 256];
    __syncthreads();
    st[tid] = v;
    __syncthreads();
    for (int off = 128; off > 0; off >>= 1) {
        if (tid < off) st[tid] += st[tid + off];
        __syncthreads();
    }
    if (tid == 0) cv[cell] = st[0];
}

// ---------------- K_slab: low-13-bit wires within an 8192-amp slab ----------
// grid: B*8 blocks (slab = cell*8 + h), 256 threads, 32 amps/thread.
template<bool INIT, bool MEASURE>
__global__ void __launch_bounds__(256)
k_slab(const float2* __restrict__ in, float2* __restrict__ outb,
       const float* __restrict__ cvbuf, const float* __restrict__ wd,
       int k, float* __restrict__ partial)
{
    __shared__ float2 tile[8192];   // 64 KB; aliased for tables / reduction
    const int tid  = threadIdx.x;
    const int slab = blockIdx.x;
    const int cell = slab >> 3, h = slab & 7;
    const float* wdk = wd + k * 16;

    float cb[13], sb[13];           // bit p (0..12) -> wire 15-p
    #pragma unroll
    for (int p = 0; p < 13; ++p) sincosf(0.5f * wdk[15 - p], &sb[p], &cb[p]);

    float2 v[32];

    if (INIT) {
        float2* coef = tile;            // [16][2]
        float2* TH   = tile + 32;       // [256]
        float2* TL   = tile + 288;      // [256]
        if (tid < 16) {
            int pr = tid >> 2, pc = tid & 3;
            const float* base = cvbuf + cell * 64;
            float m0 = base[(2 * pr) * 8 + 2 * pc];
            float m1 = base[(2 * pr) * 8 + 2 * pc + 1];
            float m2 = base[(2 * pr + 1) * 8 + 2 * pc];
            float m3 = base[(2 * pr + 1) * 8 + 2 * pc + 1];
            float xv = fmaxf(fmaxf(m0, m1), fmaxf(m2, m3));
            xv = fminf(1.f, fmaxf(-1.f, xv));
            float a  = asinf(xv);
            float bb = acosf(xv * xv);
            float sa, ca, sbb, cbb;
            sincosf(0.5f * a,  &sa, &ca);
            sincosf(0.5f * bb, &sbb, &cbb);
            coef[2 * tid + 0] = make_float2(cbb * ca, -sbb * ca);
            coef[2 * tid + 1] = make_float2(cbb * sa,  sbb * sa);
        }
        __syncthreads();
        {
            float2 ph = make_float2(1.f, 0.f), pl = make_float2(1.f, 0.f);
            #pragma unroll
            for (int i = 0; i < 8; ++i) {
                int bh = (tid >> (7 - i)) & 1;
                ph = cmul(ph, coef[2 * i + bh]);
                pl = cmul(pl, coef[2 * (8 + i) + bh]);
            }
            TH[tid] = ph; TL[tid] = pl;
        }
        __syncthreads();
        // value at logical c = T(g16(c)); g's top-8 const per thread
        unsigned cbase = ((unsigned)h << 13) | ((unsigned)tid << 5);
        unsigned g  = cbase ^ (cbase >> 1);
        float2 th   = TH[(g >> 8) & 255];
        unsigned gb = g & 255;
        #pragma unroll
        for (int j = 0; j < 32; ++j) {
            unsigned gj = gb ^ (unsigned)(j ^ (j >> 1));   // gray5(j) fold
            v[j] = cmul(th, TL[gj]);
        }
        __syncthreads();   // tables dead; tile reusable
    } else {
        const float4* g4 = (const float4*)(in + (((size_t)slab << 13) + tid * 32));
        #pragma unroll
        for (int j = 0; j < 16; ++j) {
            float4 q = g4[j];
            v[2 * j]     = make_float2(q.x, q.y);
            v[2 * j + 1] = make_float2(q.z, q.w);
        }
    }

    // bits 0..4 (wires 15..11), in-register
    #pragma unroll
    for (int b = 0; b < 5; ++b) {
        #pragma unroll
        for (int j = 0; j < 32; ++j)
            if (!(j & (1 << b))) BFLY(v[j], v[j | (1 << b)], cb[b], sb[b]);
    }

    // transpose A: register axis -> bits 5..9
    {
        int base = tid * 32;
        #pragma unroll
        for (int j = 0; j < 32; ++j) tile[sw(base + j)] = v[j];
    }
    __syncthreads();
    {
        int a = tid & 31, b3 = tid >> 5;
        #pragma unroll
        for (int j2 = 0; j2 < 32; ++j2)
            v[j2] = tile[sw(a | (j2 << 5) | (b3 << 10))];
    }
    __syncthreads();

    // bits 5..9 (wires 10..6)
    #pragma unroll
    for (int q = 0; q < 5; ++q) {
        #pragma unroll
        for (int j = 0; j < 32; ++j)
            if (!(j & (1 << q))) BFLY(v[j], v[j | (1 << q)], cb[5 + q], sb[5 + q]);
    }

    // transpose B: register axis -> bits {5,6} + {10,11,12}
    {
        int a = tid & 31, b3 = tid >> 5;
        #pragma unroll
        for (int j2 = 0; j2 < 32; ++j2)
            tile[sw(a | (j2 << 5) | (b3 << 10))] = v[j2];
    }
    __syncthreads();
    int a5 = tid & 31, d3 = tid >> 5;
    #pragma unroll
    for (int j3 = 0; j3 < 32; ++j3)
        v[j3] = tile[sw(a5 | ((j3 & 3) << 5) | (d3 << 7) | ((j3 >> 2) << 10))];

    // bits 10..12 (wires 5..3): j3 bit (2+r) <-> L bit 10+r
    #pragma unroll
    for (int r = 0; r < 3; ++r) {
        int st = 4 << r;
        #pragma unroll
        for (int j = 0; j < 32; ++j)
            if (!(j & st)) BFLY(v[j], v[j | st], cb[10 + r], sb[10 + r]);
    }

    if (!MEASURE) {
        float2* gdst = outb + ((size_t)slab << 13);
        #pragma unroll
        for (int j3 = 0; j3 < 32; ++j3)
            gdst[a5 | ((j3 & 3) << 5) | (d3 << 7) | ((j3 >> 2) << 10)] = v[j3];
    } else {
        float tot = 0.f, m5 = 0.f, m6 = 0.f, m10 = 0.f, m11 = 0.f, m12 = 0.f;
        #pragma unroll
        for (int j3 = 0; j3 < 32; ++j3) {
            float p = v[j3].x * v[j3].x + v[j3].y * v[j3].y;
            tot += p;
            if (!(j3 & 1))  m5  += p;   // L bit5
            if (!(j3 & 2))  m6  += p;   // L bit6
            if (!(j3 & 4))  m10 += p;   // L bit10
            if (!(j3 & 8))  m11 += p;   // L bit11
            if (!(j3 & 16)) m12 += p;   // L bit12
        }
        float ws16[16];
        ws16[0]  = (h & 4) ? 0.f : tot;    // wire0 <- bit15
        ws16[1]  = (h & 2) ? 0.f : tot;
        ws16[2]  = (h & 1) ? 0.f : tot;
        ws16[3]  = m12;                    // wire3 <- bit12
        ws16[4]  = m11;
        ws16[5]  = m10;
        ws16[6]  = (d3 & 4) ? 0.f : tot;   // wire6 <- bit9 = d bit2
        ws16[7]  = (d3 & 2) ? 0.f : tot;
        ws16[8]  = (d3 & 1) ? 0.f : tot;
        ws16[9]  = m6;                     // wire9  <- bit6
        ws16[10] = m5;                     // wire10 <- bit5
        ws16[11] = (a5 & 16) ? 0.f : tot;  // wire11 <- bit4
        ws16[12] = (a5 & 8)  ? 0.f : tot;
        ws16[13] = (a5 & 4)  ? 0.f : tot;
        ws16[14] = (a5 & 2)  ? 0.f : tot;
        ws16[15] = (a5 & 1)  ? 0.f : tot;

        __syncthreads();                 // all tile reads done
        float* red = (float*)tile;       // [256][17]
        #pragma unroll
        for (int i = 0; i < 16; ++i) red[tid * 17 + i] = ws16[i];
        __syncthreads();
        int ii = tid & 15, s = tid >> 4;
        float acc = 0.f;
        #pragma unroll
        for (int r = 0; r < 16; ++r) acc += red[(s * 16 + r) * 17 + ii];
        __syncthreads();
        red[s * 17 + ii] = acc;
        __syncthreads();
        if (tid < 16) {
            float t2 = 0.f;
            #pragma unroll
            for (int s2 = 0; s2 < 16; ++s2) t2 += red[s2 * 17 + tid];
            partial[(size_t)slab * 16 + tid] = t2;
        }
    }
}

// ---------------- K_mid: high-3 wires + perm (+ next layer's high-3) --------
// grid: B*32 blocks, 256 threads, 8 amps/thread (fixed low-13 L, all h).
template<bool MEASURE>
__global__ void __launch_bounds__(256)
k_mid(const float2* __restrict__ in, float2* __restrict__ outb,
      const float* __restrict__ wd, int k, int prev_high,
      float* __restrict__ partial)
{
    __shared__ float2 ex[256][5];
    __shared__ float red[256][17];
    const int tid  = threadIdx.x;
    const int cell = blockIdx.x >> 5, chunk = blockIdx.x & 31;
    const int b12 = tid >> 7, l7 = tid & 127;
    const unsigned L = ((unsigned)b12 << 12) | ((unsigned)chunk << 7) | (unsigned)l7;
    const float2* gi = in + ((size_t)cell << 16);

    float2 v[8];
    #pragma unroll
    for (int hh = 0; hh < 8; ++hh) v[hh] = gi[((size_t)hh << 13) | L];

    if (prev_high) {               // B_{k-1} wires 0..2 (bit 15-w <-> h bit 2-w)
        #pragma unroll
        for (int w = 0; w < 3; ++w) {
            float s, c; sincosf(0.5f * wd[(k - 1) * 16 + w], &s, &c);
            int st = 1 << (2 - w);
            #pragma unroll
            for (int hh = 0; hh < 8; ++hh)
                if (!(hh & st)) BFLY(v[hh], v[hh | st], c, s);
        }
    }

    if (MEASURE) {                 // ddepth==1 terminal path
        float p[8], tot = 0.f;
        #pragma unroll
        for (int hh = 0; hh < 8; ++hh) {
            p[hh] = v[hh].x * v[hh].x + v[hh].y * v[hh].y;
            tot += p[hh];
        }
        float ws16[16];
        ws16[0] = p[0] + p[1] + p[2] + p[3];
        ws16[1] = p[0] + p[1] + p[4] + p[5];
        ws16[2] = p[0] + p[2] + p[4] + p[6];
        #pragma unroll
        for (int w = 3; w < 16; ++w)
            ws16[w] = ((L >> (15 - w)) & 1) ? 0.f : tot;
        #pragma unroll
        for (int i = 0; i < 16; ++i) red[tid][i] = ws16[i];
        __syncthreads();
        int ii = tid & 15, s = tid >> 4;
        float acc = 0.f;
        #pragma unroll
        for (int r = 0; r < 16; ++r) acc += red[s * 16 + r][ii];
        __syncthreads();
        red[s][ii] = acc;
        __syncthreads();
        if (tid < 16) {
            float t2 = 0.f;
            #pragma unroll
            for (int s2 = 0; s2 < 16; ++s2) t2 += red[s2][tid];
            partial[(size_t)blockIdx.x * 16 + tid] = t2;
        }
        return;
    }

    // P_k high bits: w8[h'] = v[gray3(h')]
    float2 w8[8];
    w8[0] = v[0]; w8[1] = v[1]; w8[2] = v[3]; w8[3] = v[2];
    w8[4] = v[6]; w8[5] = v[7]; w8[6] = v[5]; w8[7] = v[4];

    // odd-h' values belong to partner fiber (L ^ 0x1000 <-> tid ^ 128)
    ex[tid ^ 128][0] = w8[1]; ex[tid ^ 128][1] = w8[3];
    ex[tid ^ 128][2] = w8[5]; ex[tid ^ 128][3] = w8[7];
    __syncthreads();
    w8[1] = ex[tid][0]; w8[3] = ex[tid][1];
    w8[5] = ex[tid][2]; w8[7] = ex[tid][3];

    // B_k wires 0..2
    #pragma unroll
    for (int w = 0; w < 3; ++w) {
        float s, c; sincosf(0.5f * wd[k * 16 + w], &s, &c);
        int st = 1 << (2 - w);
        #pragma unroll
        for (int hh = 0; hh < 8; ++hh)
            if (!(hh & st)) BFLY(w8[hh], w8[hh | st], c, s);
    }

    unsigned Lp = ginv13(L);       // owned fiber
    float2* go = outb + ((size_t)cell << 16);
    #pragma unroll
    for (int hh = 0; hh < 8; ++hh) go[((size_t)hh << 13) | Lp] = w8[hh];
}

// ---------------- K_out ------------------------------------------------------
__global__ void k_out(const float* __restrict__ partial,
                      const float* __restrict__ w_out,
                      const float* __restrict__ b_out,
                      float* __restrict__ out, int B, int odim, int P)
{
    int t = blockIdx.x * blockDim.x + threadIdx.x;
    if (t >= B * odim) return;
    int b = t / odim, o = t % odim;
    float acc = b_out[o];
    for (int i = 0; i < 16; ++i) {
        float f = 0.f;
        const float* pp = partial + (size_t)(b * P) * 16 + i;
        for (int s = 0; s < P; ++s) f += pp[s * 16];
        acc += f * w_out[i * odim + o];
    }
    out[t] = acc;
}

// ---------------------------------------------------------------------------
extern "C" void kernel_launch(void* const* d_in, const int* in_sizes, int n_in,
                              void* d_out, int out_size, void* d_ws, size_t ws_size,
                              hipStream_t stream)
{
    (void)n_in; (void)out_size; (void)ws_size;
    const float* x     = (const float*)d_in[0];
    const float* wc    = (const float*)d_in[1];
    const float* wd    = (const float*)d_in[2];
    const float* w_out = (const float*)d_in[3];
    const float* b_out = (const float*)d_in[4];
    float* out = (float*)d_out;

    const int B      = in_sizes[0] / 64;
    const int cdepth = in_sizes[1] / 9;
    const int ddepth = in_sizes[2] / 16;
    const int odim   = in_sizes[3] / 16;

    char* ws = (char*)d_ws;
    size_t off = 0;
    float* cv = (float*)(ws + off);      off += (size_t)B * 64 * sizeof(float);
    off = (off + 255) & ~(size_t)255;
    float* partial = (float*)(ws + off); off += (size_t)B * 32 * 16 * sizeof(float);
    off = (off + 255) & ~(size_t)255;
    float2* buf0 = (float2*)(ws + off);  off += (size_t)B * 65536 * sizeof(float2);
    float2* buf1 = (float2*)(ws + off);

    k_conv<<<B * 64, 256, 0, stream>>>(x, wc, cv, cdepth);

    // K1: psi0 (P0 folded) + B0 low wires
    k_slab<true, false><<<B * 8, 256, 0, stream>>>(nullptr, buf0, cv, wd, 0, nullptr);

    int P;
    if (ddepth == 1) {
        k_mid<true><<<B * 32, 256, 0, stream>>>(buf0, nullptr, wd, 1, 1, partial);
        P = 32;
    } else {
        k_mid<false><<<B * 32, 256, 0, stream>>>(buf0, buf1, wd, 1, 1, nullptr);
        float2* cur = buf1; float2* oth = buf0;
        for (int k = 2; k <= ddepth - 1; ++k) {
            k_slab<false, false><<<B * 8, 256, 0, stream>>>(cur, oth, cv, wd, k - 1, nullptr);
            { float2* t = cur; cur = oth; oth = t; }
            k_mid<false><<<B * 32, 256, 0, stream>>>(cur, oth, wd, k, 0, nullptr);
            { float2* t = cur; cur = oth; oth = t; }
        }
        k_slab<false, true><<<B * 8, 256, 0, stream>>>(cur, nullptr, cv, wd, ddepth - 1, partial);
        P = 8;
    }

    int nt = B * odim;
    k_out<<<(nt + 255) / 256, 256, 0, stream>>>(partial, w_out, b_out, out, B, odim, P);
}

// Round 4
// 62.538 us; speedup vs baseline: 1.8927x; 1.0068x over previous
//
#include <hip/hip_runtime.h>
#include <math.h>

// ---------------------------------------------------------------------------
// ConvQCL — quanvolution + 16-qubit dense quantum circuit.
//
// Conv cells (9 qubits, REAL state): one wave per cell, 8 amps/lane in
//   registers. CNOT staircase == gray map amp'(c)=amp(c^(c>>1)) -> 8 shfl;
//   RY wires 0..2 = register butterflies (j bits), wires 3..8 = shfl_xor
//   butterflies (lane bits). Zero barriers, zero LDS.
//
// Dense pipeline (ddepth=2 fast path, generic ddepth>=1):
//   K_slab<INIT>:  psi0 gray-gathered (folds perm P0) + layer-0 RY on bits
//                  0..12 (wires 3..15), registers + 2 LDS transposes. write.
//   K_mid:         B0 high (wires 0..2) + perm P1 (3-bit gray gather +
//                  partner exchange tid^128) + B1 high.  read+write.
//   K_slab<MEAS>:  layer-1 RY on bits 0..12 + fused per-wire marginals. read.
// ---------------------------------------------------------------------------

__device__ __forceinline__ float2 cmul(float2 a, float2 b) {
    return make_float2(a.x * b.x - a.y * b.y, a.x * b.y + a.y * b.x);
}
__device__ __forceinline__ unsigned ginv13(unsigned x) {
    x ^= x >> 1; x ^= x >> 2; x ^= x >> 4; x ^= x >> 8;
    return x & 0x1FFFu;
}
// LDS XOR swizzle on float2 index (breaks stride-32 bank conflicts)
__device__ __forceinline__ int sw(int i) { return i ^ ((i >> 5) & 31); }

#define BFLY(A0, A1, C, S)                                        \
    {                                                             \
        float2 t0 = (A0), t1 = (A1);                              \
        (A0) = make_float2((C)*t0.x - (S)*t1.x, (C)*t0.y - (S)*t1.y); \
        (A1) = make_float2((S)*t0.x + (C)*t1.x, (S)*t0.y + (C)*t1.y); \
    }

// ---------------- K1: conv cells — one wave per cell, barrier-free ----------
// grid: (B*64/4) blocks x 256 threads; wave w handles cell gt>>6.
__global__ void __launch_bounds__(256)
k_conv(const float* __restrict__ x, const float* __restrict__ wc,
       float* __restrict__ cv, int cdepth, int ncell)
{
    const int gt   = blockIdx.x * blockDim.x + threadIdx.x;
    const int cell = gt >> 6;
    const int lane = gt & 63;
    if (cell >= ncell) return;
    const int b = cell >> 6, pos = cell & 63, r = pos >> 3, c = pos & 7;

    // initial per-wire RY coefs (all lanes compute; loads are L1-broadcast)
    float c9[9], s9[9];
    #pragma unroll
    for (int w = 0; w < 9; ++w) {
        int kh = w / 3, kw = w % 3;
        int rr = r - 1 + kh, cc = c - 1 + kw;
        float ang = 0.f;                              // zero padding
        if (rr >= 0 && rr < 8 && cc >= 0 && cc < 8)
            ang = asinf(2.f * x[(b * 8 + rr) * 8 + cc] - 1.f);
        sincosf(0.5f * ang, &s9[w], &c9[w]);
    }

    // product state: amp(c)=prod_w coef_w[bit_{8-w}(c)], c=(j<<6)|lane
    float lprod = 1.f;
    #pragma unroll
    for (int w = 3; w < 9; ++w) {
        int bit = (lane >> (8 - w)) & 1;
        lprod *= bit ? s9[w] : c9[w];
    }
    float v[8];
    #pragma unroll
    for (int j = 0; j < 8; ++j) {
        float f = (((j >> 2) & 1) ? s9[0] : c9[0]) *
                  (((j >> 1) & 1) ? s9[1] : c9[1]) *
                  (((j >> 0) & 1) ? s9[2] : c9[2]);
        v[j] = f * lprod;
    }

    const int glane = (lane ^ (lane >> 1)) & 63;
    for (int k = 0; k < cdepth; ++k) {
        // CNOT staircase: v'[j][lane] = v[gray3(j)][glane ^ ((j&1)<<5)]
        float nv[8];
        #pragma unroll
        for (int j = 0; j < 8; ++j) {
            const int sj = j ^ (j >> 1);
            nv[j] = __shfl(v[sj], glane ^ ((j & 1) << 5), 64);
        }
        #pragma unroll
        for (int j = 0; j < 8; ++j) v[j] = nv[j];

        // RY wires 0..2 (j bits): register butterflies
        #pragma unroll
        for (int w = 0; w < 3; ++w) {
            float s, cc2; sincosf(0.5f * wc[k * 9 + w], &s, &cc2);
            const int st = 1 << (2 - w);
            #pragma unroll
            for (int j = 0; j < 8; ++j)
                if (!(j & st)) {
                    float a0 = v[j], a1 = v[j | st];
                    v[j]      = cc2 * a0 - s * a1;
                    v[j | st] = s * a0 + cc2 * a1;
                }
        }
        // RY wires 3..8 (lane bits p = 8-w): shfl_xor butterflies
        #pragma unroll
        for (int w = 3; w < 9; ++w) {
            float s, cc2; sincosf(0.5f * wc[k * 9 + w], &s, &cc2);
            const int p = 8 - w;
            const float sgn = ((lane >> p) & 1) ? s : -s;
            #pragma unroll
            for (int j = 0; j < 8; ++j) {
                float part = __shfl_xor(v[j], 1 << p, 64);
                v[j] = cc2 * v[j] + sgn * part;
            }
        }
    }

    // <Z0>: wire0 <-> j bit2
    float pz = 0.f;
    #pragma unroll
    for (int j = 0; j < 8; ++j) pz += (j & 4) ? -v[j] * v[j] : v[j] * v[j];
    #pragma unroll
    for (int off = 32; off > 0; off >>= 1) pz += __shfl_xor(pz, off, 64);
    if (lane == 0) cv[cell] = pz;
}

// ---------------- K_slab: low-13-bit wires within an 8192-amp slab ----------
// grid: B*8 blocks (slab = cell*8 + h), 256 threads, 32 amps/thread.
template<bool INIT, bool MEASURE>
__global__ void __launch_bounds__(256)
k_slab(const float2* __restrict__ in, float2* __restrict__ outb,
       const float* __restrict__ cvbuf, const float* __restrict__ wd,
       int k, float* __restrict__ partial)
{
    __shared__ float2 tile[8192];   // 64 KB; aliased for tables / reduction
    const int tid  = threadIdx.x;
    const int slab = blockIdx.x;
    const int cell = slab >> 3, h = slab & 7;
    const float* wdk = wd + k * 16;

    float cb[13], sb[13];           // bit p (0..12) -> wire 15-p
    #pragma unroll
    for (int p = 0; p < 13; ++p) sincosf(0.5f * wdk[15 - p], &sb[p], &cb[p]);

    float2 v[32];

    if (INIT) {
        float2* coef = tile;            // [16][2]
        float2* TH   = tile + 32;       // [256]
        float2* TL   = tile + 288;      // [256]
        if (tid < 16) {
            int pr = tid >> 2, pc = tid & 3;
            const float* base = cvbuf + cell * 64;
            float m0 = base[(2 * pr) * 8 + 2 * pc];
            float m1 = base[(2 * pr) * 8 + 2 * pc + 1];
            float m2 = base[(2 * pr + 1) * 8 + 2 * pc];
            float m3 = base[(2 * pr + 1) * 8 + 2 * pc + 1];
            float xv = fmaxf(fmaxf(m0, m1), fmaxf(m2, m3));
            xv = fminf(1.f, fmaxf(-1.f, xv));
            float a  = asinf(xv);
            float bb = acosf(xv * xv);
            float sa, ca, sbb, cbb;
            sincosf(0.5f * a,  &sa, &ca);
            sincosf(0.5f * bb, &sbb, &cbb);
            coef[2 * tid + 0] = make_float2(cbb * ca, -sbb * ca);
            coef[2 * tid + 1] = make_float2(cbb * sa,  sbb * sa);
        }
        __syncthreads();
        {
            float2 ph = make_float2(1.f, 0.f), pl = make_float2(1.f, 0.f);
            #pragma unroll
            for (int i = 0; i < 8; ++i) {
                int bh = (tid >> (7 - i)) & 1;
                ph = cmul(ph, coef[2 * i + bh]);
                pl = cmul(pl, coef[2 * (8 + i) + bh]);
            }
            TH[tid] = ph; TL[tid] = pl;
        }
        __syncthreads();
        // value at logical c = T(g16(c)); g's top-8 const per thread
        unsigned cbase = ((unsigned)h << 13) | ((unsigned)tid << 5);
        unsigned g  = cbase ^ (cbase >> 1);
        float2 th   = TH[(g >> 8) & 255];
        unsigned gb = g & 255;
        #pragma unroll
        for (int j = 0; j < 32; ++j) {
            unsigned gj = gb ^ (unsigned)(j ^ (j >> 1));   // gray5(j) fold
            v[j] = cmul(th, TL[gj]);
        }
        __syncthreads();   // tables dead; tile reusable
    } else {
        const float4* g4 = (const float4*)(in + (((size_t)slab << 13) + tid * 32));
        #pragma unroll
        for (int j = 0; j < 16; ++j) {
            float4 q = g4[j];
            v[2 * j]     = make_float2(q.x, q.y);
            v[2 * j + 1] = make_float2(q.z, q.w);
        }
    }

    // bits 0..4 (wires 15..11), in-register
    #pragma unroll
    for (int b = 0; b < 5; ++b) {
        #pragma unroll
        for (int j = 0; j < 32; ++j)
            if (!(j & (1 << b))) BFLY(v[j], v[j | (1 << b)], cb[b], sb[b]);
    }

    // transpose A: register axis -> bits 5..9
    {
        int base = tid * 32;
        #pragma unroll
        for (int j = 0; j < 32; ++j) tile[sw(base + j)] = v[j];
    }
    __syncthreads();
    {
        int a = tid & 31, b3 = tid >> 5;
        #pragma unroll
        for (int j2 = 0; j2 < 32; ++j2)
            v[j2] = tile[sw(a | (j2 << 5) | (b3 << 10))];
    }
    __syncthreads();

    // bits 5..9 (wires 10..6)
    #pragma unroll
    for (int q = 0; q < 5; ++q) {
        #pragma unroll
        for (int j = 0; j < 32; ++j)
            if (!(j & (1 << q))) BFLY(v[j], v[j | (1 << q)], cb[5 + q], sb[5 + q]);
    }

    // transpose B: register axis -> bits {5,6} + {10,11,12}
    {
        int a = tid & 31, b3 = tid >> 5;
        #pragma unroll
        for (int j2 = 0; j2 < 32; ++j2)
            tile[sw(a | (j2 << 5) | (b3 << 10))] = v[j2];
    }
    __syncthreads();
    int a5 = tid & 31, d3 = tid >> 5;
    #pragma unroll
    for (int j3 = 0; j3 < 32; ++j3)
        v[j3] = tile[sw(a5 | ((j3 & 3) << 5) | (d3 << 7) | ((j3 >> 2) << 10))];

    // bits 10..12 (wires 5..3): j3 bit (2+r) <-> L bit 10+r
    #pragma unroll
    for (int r = 0; r < 3; ++r) {
        int st = 4 << r;
        #pragma unroll
        for (int j = 0; j < 32; ++j)
            if (!(j & st)) BFLY(v[j], v[j | st], cb[10 + r], sb[10 + r]);
    }

    if (!MEASURE) {
        float2* gdst = outb + ((size_t)slab << 13);
        #pragma unroll
        for (int j3 = 0; j3 < 32; ++j3)
            gdst[a5 | ((j3 & 3) << 5) | (d3 << 7) | ((j3 >> 2) << 10)] = v[j3];
    } else {
        float tot = 0.f, m5 = 0.f, m6 = 0.f, m10 = 0.f, m11 = 0.f, m12 = 0.f;
        #pragma unroll
        for (int j3 = 0; j3 < 32; ++j3) {
            float p = v[j3].x * v[j3].x + v[j3].y * v[j3].y;
            tot += p;
            if (!(j3 & 1))  m5  += p;   // L bit5
            if (!(j3 & 2))  m6  += p;   // L bit6
            if (!(j3 & 4))  m10 += p;   // L bit10
            if (!(j3 & 8))  m11 += p;   // L bit11
            if (!(j3 & 16)) m12 += p;   // L bit12
        }
        float ws16[16];
        ws16[0]  = (h & 4) ? 0.f : tot;    // wire0 <- bit15
        ws16[1]  = (h & 2) ? 0.f : tot;
        ws16[2]  = (h & 1) ? 0.f : tot;
        ws16[3]  = m12;                    // wire3 <- bit12
        ws16[4]  = m11;
        ws16[5]  = m10;
        ws16[6]  = (d3 & 4) ? 0.f : tot;   // wire6 <- bit9 = d bit2
        ws16[7]  = (d3 & 2) ? 0.f : tot;
        ws16[8]  = (d3 & 1) ? 0.f : tot;
        ws16[9]  = m6;                     // wire9  <- bit6
        ws16[10] = m5;                     // wire10 <- bit5
        ws16[11] = (a5 & 16) ? 0.f : tot;  // wire11 <- bit4
        ws16[12] = (a5 & 8)  ? 0.f : tot;
        ws16[13] = (a5 & 4)  ? 0.f : tot;
        ws16[14] = (a5 & 2)  ? 0.f : tot;
        ws16[15] = (a5 & 1)  ? 0.f : tot;

        __syncthreads();                 // all tile reads done
        float* red = (float*)tile;       // [256][17]
        #pragma unroll
        for (int i = 0; i < 16; ++i) red[tid * 17 + i] = ws16[i];
        __syncthreads();
        int ii = tid & 15, s = tid >> 4;
        float acc = 0.f;
        #pragma unroll
        for (int r = 0; r < 16; ++r) acc += red[(s * 16 + r) * 17 + ii];
        __syncthreads();
        red[s * 17 + ii] = acc;
        __syncthreads();
        if (tid < 16) {
            float t2 = 0.f;
            #pragma unroll
            for (int s2 = 0; s2 < 16; ++s2) t2 += red[s2 * 17 + tid];
            partial[(size_t)slab * 16 + tid] = t2;
        }
    }
}

// ---------------- K_mid: high-3 wires + perm (+ next layer's high-3) --------
// grid: B*32 blocks, 256 threads, 8 amps/thread (fixed low-13 L, all h).
template<bool MEASURE>
__global__ void __launch_bounds__(256)
k_mid(const float2* __restrict__ in, float2* __restrict__ outb,
      const float* __restrict__ wd, int k, int prev_high,
      float* __restrict__ partial)
{
    __shared__ float2 ex[256][5];
    __shared__ float red[256][17];
    const int tid  = threadIdx.x;
    const int cell = blockIdx.x >> 5, chunk = blockIdx.x & 31;
    const int b12 = tid >> 7, l7 = tid & 127;
    const unsigned L = ((unsigned)b12 << 12) | ((unsigned)chunk << 7) | (unsigned)l7;
    const float2* gi = in + ((size_t)cell << 16);

    float2 v[8];
    #pragma unroll
    for (int hh = 0; hh < 8; ++hh) v[hh] = gi[((size_t)hh << 13) | L];

    if (prev_high) {               // B_{k-1} wires 0..2 (bit 15-w <-> h bit 2-w)
        #pragma unroll
        for (int w = 0; w < 3; ++w) {
            float s, c; sincosf(0.5f * wd[(k - 1) * 16 + w], &s, &c);
            int st = 1 << (2 - w);
            #pragma unroll
            for (int hh = 0; hh < 8; ++hh)
                if (!(hh & st)) BFLY(v[hh], v[hh | st], c, s);
        }
    }

    if (MEASURE) {                 // ddepth==1 terminal path
        float p[8], tot = 0.f;
        #pragma unroll
        for (int hh = 0; hh < 8; ++hh) {
            p[hh] = v[hh].x * v[hh].x + v[hh].y * v[hh].y;
            tot += p[hh];
        }
        float ws16[16];
        ws16[0] = p[0] + p[1] + p[2] + p[3];
        ws16[1] = p[0] + p[1] + p[4] + p[5];
        ws16[2] = p[0] + p[2] + p[4] + p[6];
        #pragma unroll
        for (int w = 3; w < 16; ++w)
            ws16[w] = ((L >> (15 - w)) & 1) ? 0.f : tot;
        #pragma unroll
        for (int i = 0; i < 16; ++i) red[tid][i] = ws16[i];
        __syncthreads();
        int ii = tid & 15, s = tid >> 4;
        float acc = 0.f;
        #pragma unroll
        for (int r = 0; r < 16; ++r) acc += red[s * 16 + r][ii];
        __syncthreads();
        red[s][ii] = acc;
        __syncthreads();
        if (tid < 16) {
            float t2 = 0.f;
            #pragma unroll
            for (int s2 = 0; s2 < 16; ++s2) t2 += red[s2][tid];
            partial[(size_t)blockIdx.x * 16 + tid] = t2;
        }
        return;
    }

    // P_k high bits: w8[h'] = v[gray3(h')]
    float2 w8[8];
    w8[0] = v[0]; w8[1] = v[1]; w8[2] = v[3]; w8[3] = v[2];
    w8[4] = v[6]; w8[5] = v[7]; w8[6] = v[5]; w8[7] = v[4];

    // odd-h' values belong to partner fiber (L ^ 0x1000 <-> tid ^ 128)
    ex[tid ^ 128][0] = w8[1]; ex[tid ^ 128][1] = w8[3];
    ex[tid ^ 128][2] = w8[5]; ex[tid ^ 128][3] = w8[7];
    __syncthreads();
    w8[1] = ex[tid][0]; w8[3] = ex[tid][1];
    w8[5] = ex[tid][2]; w8[7] = ex[tid][3];

    // B_k wires 0..2
    #pragma unroll
    for (int w = 0; w < 3; ++w) {
        float s, c; sincosf(0.5f * wd[k * 16 + w], &s, &c);
        int st = 1 << (2 - w);
        #pragma unroll
        for (int hh = 0; hh < 8; ++hh)
            if (!(hh & st)) BFLY(w8[hh], w8[hh | st], c, s);
    }

    unsigned Lp = ginv13(L);       // owned fiber
    float2* go = outb + ((size_t)cell << 16);
    #pragma unroll
    for (int hh = 0; hh < 8; ++hh) go[((size_t)hh << 13) | Lp] = w8[hh];
}

// ---------------- K_out ------------------------------------------------------
__global__ void k_out(const float* __restrict__ partial,
                      const float* __restrict__ w_out,
                      const float* __restrict__ b_out,
                      float* __restrict__ out, int B, int odim, int P)
{
    int t = blockIdx.x * blockDim.x + threadIdx.x;
    if (t >= B * odim) return;
    int b = t / odim, o = t % odim;
    float acc = b_out[o];
    for (int i = 0; i < 16; ++i) {
        float f = 0.f;
        const float* pp = partial + (size_t)(b * P) * 16 + i;
        for (int s = 0; s < P; ++s) f += pp[s * 16];
        acc += f * w_out[i * odim + o];
    }
    out[t] = acc;
}

// ---------------------------------------------------------------------------
extern "C" void kernel_launch(void* const* d_in, const int* in_sizes, int n_in,
                              void* d_out, int out_size, void* d_ws, size_t ws_size,
                              hipStream_t stream)
{
    (void)n_in; (void)out_size; (void)ws_size;
    const float* x     = (const float*)d_in[0];
    const float* wc    = (const float*)d_in[1];
    const float* wd    = (const float*)d_in[2];
    const float* w_out = (const float*)d_in[3];
    const float* b_out = (const float*)d_in[4];
    float* out = (float*)d_out;

    const int B      = in_sizes[0] / 64;
    const int cdepth = in_sizes[1] / 9;
    const int ddepth = in_sizes[2] / 16;
    const int odim   = in_sizes[3] / 16;

    char* ws = (char*)d_ws;
    size_t off = 0;
    float* cv = (float*)(ws + off);      off += (size_t)B * 64 * sizeof(float);
    off = (off + 255) & ~(size_t)255;
    float* partial = (float*)(ws + off); off += (size_t)B * 32 * 16 * sizeof(float);
    off = (off + 255) & ~(size_t)255;
    float2* buf0 = (float2*)(ws + off);  off += (size_t)B * 65536 * sizeof(float2);
    float2* buf1 = (float2*)(ws + off);

    const int ncell = B * 64;
    k_conv<<<(ncell * 64 + 255) / 256, 256, 0, stream>>>(x, wc, cv, cdepth, ncell);

    // K1: psi0 (P0 folded) + B0 low wires
    k_slab<true, false><<<B * 8, 256, 0, stream>>>(nullptr, buf0, cv, wd, 0, nullptr);

    int P;
    if (ddepth == 1) {
        k_mid<true><<<B * 32, 256, 0, stream>>>(buf0, nullptr, wd, 1, 1, partial);
        P = 32;
    } else {
        k_mid<false><<<B * 32, 256, 0, stream>>>(buf0, buf1, wd, 1, 1, nullptr);
        float2* cur = buf1; float2* oth = buf0;
        for (int k = 2; k <= ddepth - 1; ++k) {
            k_slab<false, false><<<B * 8, 256, 0, stream>>>(cur, oth, cv, wd, k - 1, nullptr);
            { float2* t = cur; cur = oth; oth = t; }
            k_mid<false><<<B * 32, 256, 0, stream>>>(cur, oth, wd, k, 0, nullptr);
            { float2* t = cur; cur = oth; oth = t; }
        }
        k_slab<false, true><<<B * 8, 256, 0, stream>>>(cur, nullptr, cv, wd, ddepth - 1, partial);
        P = 8;
    }

    int nt = B * odim;
    k_out<<<(nt + 255) / 256, 256, 0, stream>>>(partial, w_out, b_out, out, B, odim, P);
}

// Round 5
// 55.258 us; speedup vs baseline: 2.1421x; 1.1317x over previous
//
#include <hip/hip_runtime.h>
#include <hip/hip_fp16.h>
#include <math.h>

// ---------------------------------------------------------------------------
// ConvQCL — quanvolution + 16-qubit dense quantum circuit.
//
// Conv cells (9 qubits, REAL state): one wave per cell, 8 amps/lane in
//   registers; CNOT staircase == gray map -> shfl; RY = register/shfl_xor
//   butterflies. Zero barriers, zero LDS.
//
// Dense pipeline (ddepth=2 fast path, generic ddepth>=1):
//   K_slab<INIT>:  psi0 gray-gathered (folds perm P0) + layer-0 RY on bits
//                  0..12 (wires 3..15), registers + 2 LDS transposes. write.
//   K_mid:         B0 high (wires 0..2) + perm P1 (3-bit gray gather +
//                  partner exchange tid^128) + B1 high.  read+write.
//   K_slab<MEAS>:  layer-1 RY on bits 0..12 + fused per-wire marginals. read.
// Intermediate state stored as __half2 (re,im) — f32 compute, fp16 storage.
// Output threshold 1.3e-2 >> fp16-induced ~1e-3.
// ---------------------------------------------------------------------------

__device__ __forceinline__ float2 cmul(float2 a, float2 b) {
    return make_float2(a.x * b.x - a.y * b.y, a.x * b.y + a.y * b.x);
}
__device__ __forceinline__ unsigned ginv13(unsigned x) {
    x ^= x >> 1; x ^= x >> 2; x ^= x >> 4; x ^= x >> 8;
    return x & 0x1FFFu;
}
__device__ __forceinline__ int sw(int i) { return i ^ ((i >> 5) & 31); }

__device__ __forceinline__ __half2 pack(float2 f) {
    return __floats2half2_rn(f.x, f.y);
}
__device__ __forceinline__ float2 unpack(__half2 h) {
    return __half22float2(h);
}

#define BFLY(A0, A1, C, S)                                        \
    {                                                             \
        float2 t0 = (A0), t1 = (A1);                              \
        (A0) = make_float2((C)*t0.x - (S)*t1.x, (C)*t0.y - (S)*t1.y); \
        (A1) = make_float2((S)*t0.x + (C)*t1.x, (S)*t0.y + (C)*t1.y); \
    }

// ---------------- K1: conv cells — one wave per cell, barrier-free ----------
__global__ void __launch_bounds__(256)
k_conv(const float* __restrict__ x, const float* __restrict__ wc,
       float* __restrict__ cv, int cdepth, int ncell)
{
    const int gt   = blockIdx.x * blockDim.x + threadIdx.x;
    const int cell = gt >> 6;
    const int lane = gt & 63;
    if (cell >= ncell) return;
    const int b = cell >> 6, pos = cell & 63, r = pos >> 3, c = pos & 7;

    float c9[9], s9[9];
    #pragma unroll
    for (int w = 0; w < 9; ++w) {
        int kh = w / 3, kw = w % 3;
        int rr = r - 1 + kh, cc = c - 1 + kw;
        float ang = 0.f;
        if (rr >= 0 && rr < 8 && cc >= 0 && cc < 8)
            ang = asinf(2.f * x[(b * 8 + rr) * 8 + cc] - 1.f);
        sincosf(0.5f * ang, &s9[w], &c9[w]);
    }

    float lprod = 1.f;
    #pragma unroll
    for (int w = 3; w < 9; ++w) {
        int bit = (lane >> (8 - w)) & 1;
        lprod *= bit ? s9[w] : c9[w];
    }
    float v[8];
    #pragma unroll
    for (int j = 0; j < 8; ++j) {
        float f = (((j >> 2) & 1) ? s9[0] : c9[0]) *
                  (((j >> 1) & 1) ? s9[1] : c9[1]) *
                  (((j >> 0) & 1) ? s9[2] : c9[2]);
        v[j] = f * lprod;
    }

    const int glane = (lane ^ (lane >> 1)) & 63;
    for (int k = 0; k < cdepth; ++k) {
        float nv[8];
        #pragma unroll
        for (int j = 0; j < 8; ++j) {
            const int sj = j ^ (j >> 1);
            nv[j] = __shfl(v[sj], glane ^ ((j & 1) << 5), 64);
        }
        #pragma unroll
        for (int j = 0; j < 8; ++j) v[j] = nv[j];

        #pragma unroll
        for (int w = 0; w < 3; ++w) {
            float s, cc2; sincosf(0.5f * wc[k * 9 + w], &s, &cc2);
            const int st = 1 << (2 - w);
            #pragma unroll
            for (int j = 0; j < 8; ++j)
                if (!(j & st)) {
                    float a0 = v[j], a1 = v[j | st];
                    v[j]      = cc2 * a0 - s * a1;
                    v[j | st] = s * a0 + cc2 * a1;
                }
        }
        #pragma unroll
        for (int w = 3; w < 9; ++w) {
            float s, cc2; sincosf(0.5f * wc[k * 9 + w], &s, &cc2);
            const int p = 8 - w;
            const float sgn = ((lane >> p) & 1) ? s : -s;
            #pragma unroll
            for (int j = 0; j < 8; ++j) {
                float part = __shfl_xor(v[j], 1 << p, 64);
                v[j] = cc2 * v[j] + sgn * part;
            }
        }
    }

    float pz = 0.f;
    #pragma unroll
    for (int j = 0; j < 8; ++j) pz += (j & 4) ? -v[j] * v[j] : v[j] * v[j];
    #pragma unroll
    for (int off = 32; off > 0; off >>= 1) pz += __shfl_xor(pz, off, 64);
    if (lane == 0) cv[cell] = pz;
}

// ---------------- K_slab: low-13-bit wires within an 8192-amp slab ----------
// grid: B*8 blocks (slab = cell*8 + h), 256 threads, 32 amps/thread.
template<bool INIT, bool MEASURE>
__global__ void __launch_bounds__(256)
k_slab(const __half2* __restrict__ in, __half2* __restrict__ outb,
       const float* __restrict__ cvbuf, const float* __restrict__ wd,
       int k, float* __restrict__ partial)
{
    __shared__ float2 tile[8192];   // 64 KB; aliased for tables / reduction
    const int tid  = threadIdx.x;
    const int slab = blockIdx.x;
    const int cell = slab >> 3, h = slab & 7;
    const float* wdk = wd + k * 16;

    float cb[13], sb[13];           // bit p (0..12) -> wire 15-p
    #pragma unroll
    for (int p = 0; p < 13; ++p) sincosf(0.5f * wdk[15 - p], &sb[p], &cb[p]);

    float2 v[32];

    if (INIT) {
        float2* coef = tile;            // [16][2]
        float2* TH   = tile + 32;       // [256]
        float2* TL   = tile + 288;      // [256]
        if (tid < 16) {
            int pr = tid >> 2, pc = tid & 3;
            const float* base = cvbuf + cell * 64;
            float m0 = base[(2 * pr) * 8 + 2 * pc];
            float m1 = base[(2 * pr) * 8 + 2 * pc + 1];
            float m2 = base[(2 * pr + 1) * 8 + 2 * pc];
            float m3 = base[(2 * pr + 1) * 8 + 2 * pc + 1];
            float xv = fmaxf(fmaxf(m0, m1), fmaxf(m2, m3));
            xv = fminf(1.f, fmaxf(-1.f, xv));
            float a  = asinf(xv);
            float bb = acosf(xv * xv);
            float sa, ca, sbb, cbb;
            sincosf(0.5f * a,  &sa, &ca);
            sincosf(0.5f * bb, &sbb, &cbb);
            coef[2 * tid + 0] = make_float2(cbb * ca, -sbb * ca);
            coef[2 * tid + 1] = make_float2(cbb * sa,  sbb * sa);
        }
        __syncthreads();
        {
            float2 ph = make_float2(1.f, 0.f), pl = make_float2(1.f, 0.f);
            #pragma unroll
            for (int i = 0; i < 8; ++i) {
                int bh = (tid >> (7 - i)) & 1;
                ph = cmul(ph, coef[2 * i + bh]);
                pl = cmul(pl, coef[2 * (8 + i) + bh]);
            }
            TH[tid] = ph; TL[tid] = pl;
        }
        __syncthreads();
        unsigned cbase = ((unsigned)h << 13) | ((unsigned)tid << 5);
        unsigned g  = cbase ^ (cbase >> 1);
        float2 th   = TH[(g >> 8) & 255];
        unsigned gb = g & 255;
        #pragma unroll
        for (int j = 0; j < 32; ++j) {
            unsigned gj = gb ^ (unsigned)(j ^ (j >> 1));   // gray5(j) fold
            v[j] = cmul(th, TL[gj]);
        }
        __syncthreads();   // tables dead; tile reusable
    } else {
        const uint4* g4 = (const uint4*)(in + (((size_t)slab << 13) + tid * 32));
        #pragma unroll
        for (int j = 0; j < 8; ++j) {
            uint4 q = g4[j];
            v[4 * j + 0] = unpack(*reinterpret_cast<__half2*>(&q.x));
            v[4 * j + 1] = unpack(*reinterpret_cast<__half2*>(&q.y));
            v[4 * j + 2] = unpack(*reinterpret_cast<__half2*>(&q.z));
            v[4 * j + 3] = unpack(*reinterpret_cast<__half2*>(&q.w));
        }
    }

    // bits 0..4 (wires 15..11), in-register
    #pragma unroll
    for (int b = 0; b < 5; ++b) {
        #pragma unroll
        for (int j = 0; j < 32; ++j)
            if (!(j & (1 << b))) BFLY(v[j], v[j | (1 << b)], cb[b], sb[b]);
    }

    // transpose A: register axis -> bits 5..9
    {
        int base = tid * 32;
        #pragma unroll
        for (int j = 0; j < 32; ++j) tile[sw(base + j)] = v[j];
    }
    __syncthreads();
    {
        int a = tid & 31, b3 = tid >> 5;
        #pragma unroll
        for (int j2 = 0; j2 < 32; ++j2)
            v[j2] = tile[sw(a | (j2 << 5) | (b3 << 10))];
    }
    __syncthreads();

    // bits 5..9 (wires 10..6)
    #pragma unroll
    for (int q = 0; q < 5; ++q) {
        #pragma unroll
        for (int j = 0; j < 32; ++j)
            if (!(j & (1 << q))) BFLY(v[j], v[j | (1 << q)], cb[5 + q], sb[5 + q]);
    }

    // transpose B: register axis -> bits {5,6} + {10,11,12}
    {
        int a = tid & 31, b3 = tid >> 5;
        #pragma unroll
        for (int j2 = 0; j2 < 32; ++j2)
            tile[sw(a | (j2 << 5) | (b3 << 10))] = v[j2];
    }
    __syncthreads();
    int a5 = tid & 31, d3 = tid >> 5;
    #pragma unroll
    for (int j3 = 0; j3 < 32; ++j3)
        v[j3] = tile[sw(a5 | ((j3 & 3) << 5) | (d3 << 7) | ((j3 >> 2) << 10))];

    // bits 10..12 (wires 5..3)
    #pragma unroll
    for (int r = 0; r < 3; ++r) {
        int st = 4 << r;
        #pragma unroll
        for (int j = 0; j < 32; ++j)
            if (!(j & st)) BFLY(v[j], v[j | st], cb[10 + r], sb[10 + r]);
    }

    if (!MEASURE) {
        __half2* gdst = outb + ((size_t)slab << 13);
        #pragma unroll
        for (int j3 = 0; j3 < 32; ++j3)
            gdst[a5 | ((j3 & 3) << 5) | (d3 << 7) | ((j3 >> 2) << 10)] = pack(v[j3]);
    } else {
        float tot = 0.f, m5 = 0.f, m6 = 0.f, m10 = 0.f, m11 = 0.f, m12 = 0.f;
        #pragma unroll
        for (int j3 = 0; j3 < 32; ++j3) {
            float p = v[j3].x * v[j3].x + v[j3].y * v[j3].y;
            tot += p;
            if (!(j3 & 1))  m5  += p;
            if (!(j3 & 2))  m6  += p;
            if (!(j3 & 4))  m10 += p;
            if (!(j3 & 8))  m11 += p;
            if (!(j3 & 16)) m12 += p;
        }
        float ws16[16];
        ws16[0]  = (h & 4) ? 0.f : tot;
        ws16[1]  = (h & 2) ? 0.f : tot;
        ws16[2]  = (h & 1) ? 0.f : tot;
        ws16[3]  = m12;
        ws16[4]  = m11;
        ws16[5]  = m10;
        ws16[6]  = (d3 & 4) ? 0.f : tot;
        ws16[7]  = (d3 & 2) ? 0.f : tot;
        ws16[8]  = (d3 & 1) ? 0.f : tot;
        ws16[9]  = m6;
        ws16[10] = m5;
        ws16[11] = (a5 & 16) ? 0.f : tot;
        ws16[12] = (a5 & 8)  ? 0.f : tot;
        ws16[13] = (a5 & 4)  ? 0.f : tot;
        ws16[14] = (a5 & 2)  ? 0.f : tot;
        ws16[15] = (a5 & 1)  ? 0.f : tot;

        __syncthreads();
        float* red = (float*)tile;       // [256][17]
        #pragma unroll
        for (int i = 0; i < 16; ++i) red[tid * 17 + i] = ws16[i];
        __syncthreads();
        int ii = tid & 15, s = tid >> 4;
        float acc = 0.f;
        #pragma unroll
        for (int r = 0; r < 16; ++r) acc += red[(s * 16 + r) * 17 + ii];
        __syncthreads();
        red[s * 17 + ii] = acc;
        __syncthreads();
        if (tid < 16) {
            float t2 = 0.f;
            #pragma unroll
            for (int s2 = 0; s2 < 16; ++s2) t2 += red[s2 * 17 + tid];
            partial[(size_t)slab * 16 + tid] = t2;
        }
    }
}

// ---------------- K_mid: high-3 wires + perm (+ next layer's high-3) --------
template<bool MEASURE>
__global__ void __launch_bounds__(256)
k_mid(const __half2* __restrict__ in, __half2* __restrict__ outb,
      const float* __restrict__ wd, int k, int prev_high,
      float* __restrict__ partial)
{
    __shared__ float2 ex[256][5];
    __shared__ float red[256][17];
    const int tid  = threadIdx.x;
    const int cell = blockIdx.x >> 5, chunk = blockIdx.x & 31;
    const int b12 = tid >> 7, l7 = tid & 127;
    const unsigned L = ((unsigned)b12 << 12) | ((unsigned)chunk << 7) | (unsigned)l7;
    const __half2* gi = in + ((size_t)cell << 16);

    float2 v[8];
    #pragma unroll
    for (int hh = 0; hh < 8; ++hh) v[hh] = unpack(gi[((size_t)hh << 13) | L]);

    if (prev_high) {
        #pragma unroll
        for (int w = 0; w < 3; ++w) {
            float s, c; sincosf(0.5f * wd[(k - 1) * 16 + w], &s, &c);
            int st = 1 << (2 - w);
            #pragma unroll
            for (int hh = 0; hh < 8; ++hh)
                if (!(hh & st)) BFLY(v[hh], v[hh | st], c, s);
        }
    }

    if (MEASURE) {
        float p[8], tot = 0.f;
        #pragma unroll
        for (int hh = 0; hh < 8; ++hh) {
            p[hh] = v[hh].x * v[hh].x + v[hh].y * v[hh].y;
            tot += p[hh];
        }
        float ws16[16];
        ws16[0] = p[0] + p[1] + p[2] + p[3];
        ws16[1] = p[0] + p[1] + p[4] + p[5];
        ws16[2] = p[0] + p[2] + p[4] + p[6];
        #pragma unroll
        for (int w = 3; w < 16; ++w)
            ws16[w] = ((L >> (15 - w)) & 1) ? 0.f : tot;
        #pragma unroll
        for (int i = 0; i < 16; ++i) red[tid][i] = ws16[i];
        __syncthreads();
        int ii = tid & 15, s = tid >> 4;
        float acc = 0.f;
        #pragma unroll
        for (int r = 0; r < 16; ++r) acc += red[s * 16 + r][ii];
        __syncthreads();
        red[s][ii] = acc;
        __syncthreads();
        if (tid < 16) {
            float t2 = 0.f;
            #pragma unroll
            for (int s2 = 0; s2 < 16; ++s2) t2 += red[s2][tid];
            partial[(size_t)blockIdx.x * 16 + tid] = t2;
        }
        return;
    }

    // P_k high bits: w8[h'] = v[gray3(h')]
    float2 w8[8];
    w8[0] = v[0]; w8[1] = v[1]; w8[2] = v[3]; w8[3] = v[2];
    w8[4] = v[6]; w8[5] = v[7]; w8[6] = v[5]; w8[7] = v[4];

    ex[tid ^ 128][0] = w8[1]; ex[tid ^ 128][1] = w8[3];
    ex[tid ^ 128][2] = w8[5]; ex[tid ^ 128][3] = w8[7];
    __syncthreads();
    w8[1] = ex[tid][0]; w8[3] = ex[tid][1];
    w8[5] = ex[tid][2]; w8[7] = ex[tid][3];

    #pragma unroll
    for (int w = 0; w < 3; ++w) {
        float s, c; sincosf(0.5f * wd[k * 16 + w], &s, &c);
        int st = 1 << (2 - w);
        #pragma unroll
        for (int hh = 0; hh < 8; ++hh)
            if (!(hh & st)) BFLY(w8[hh], w8[hh | st], c, s);
    }

    unsigned Lp = ginv13(L);
    __half2* go = outb + ((size_t)cell << 16);
    #pragma unroll
    for (int hh = 0; hh < 8; ++hh) go[((size_t)hh << 13) | Lp] = pack(w8[hh]);
}

// ---------------- K_out ------------------------------------------------------
__global__ void k_out(const float* __restrict__ partial,
                      const float* __restrict__ w_out,
                      const float* __restrict__ b_out,
                      float* __restrict__ out, int B, int odim, int P)
{
    int t = blockIdx.x * blockDim.x + threadIdx.x;
    if (t >= B * odim) return;
    int b = t / odim, o = t % odim;
    float acc = b_out[o];
    for (int i = 0; i < 16; ++i) {
        float f = 0.f;
        const float* pp = partial + (size_t)(b * P) * 16 + i;
        for (int s = 0; s < P; ++s) f += pp[s * 16];
        acc += f * w_out[i * odim + o];
    }
    out[t] = acc;
}

// ---------------------------------------------------------------------------
extern "C" void kernel_launch(void* const* d_in, const int* in_sizes, int n_in,
                              void* d_out, int out_size, void* d_ws, size_t ws_size,
                              hipStream_t stream)
{
    (void)n_in; (void)out_size; (void)ws_size;
    const float* x     = (const float*)d_in[0];
    const float* wc    = (const float*)d_in[1];
    const float* wd    = (const float*)d_in[2];
    const float* w_out = (const float*)d_in[3];
    const float* b_out = (const float*)d_in[4];
    float* out = (float*)d_out;

    const int B      = in_sizes[0] / 64;
    const int cdepth = in_sizes[1] / 9;
    const int ddepth = in_sizes[2] / 16;
    const int odim   = in_sizes[3] / 16;

    char* ws = (char*)d_ws;
    size_t off = 0;
    float* cv = (float*)(ws + off);      off += (size_t)B * 64 * sizeof(float);
    off = (off + 255) & ~(size_t)255;
    float* partial = (float*)(ws + off); off += (size_t)B * 32 * 16 * sizeof(float);
    off = (off + 255) & ~(size_t)255;
    __half2* buf0 = (__half2*)(ws + off); off += (size_t)B * 65536 * sizeof(__half2);
    __half2* buf1 = (__half2*)(ws + off);

    const int ncell = B * 64;
    k_conv<<<(ncell * 64 + 255) / 256, 256, 0, stream>>>(x, wc, cv, cdepth, ncell);

    // K1: psi0 (P0 folded) + B0 low wires
    k_slab<true, false><<<B * 8, 256, 0, stream>>>(nullptr, buf0, cv, wd, 0, nullptr);

    int P;
    if (ddepth == 1) {
        k_mid<true><<<B * 32, 256, 0, stream>>>(buf0, nullptr, wd, 1, 1, partial);
        P = 32;
    } else {
        k_mid<false><<<B * 32, 256, 0, stream>>>(buf0, buf1, wd, 1, 1, nullptr);
        __half2* cur = buf1; __half2* oth = buf0;
        for (int k = 2; k <= ddepth - 1; ++k) {
            k_slab<false, false><<<B * 8, 256, 0, stream>>>(cur, oth, cv, wd, k - 1, nullptr);
            { __half2* t = cur; cur = oth; oth = t; }
            k_mid<false><<<B * 32, 256, 0, stream>>>(cur, oth, wd, k, 0, nullptr);
            { __half2* t = cur; cur = oth; oth = t; }
        }
        k_slab<false, true><<<B * 8, 256, 0, stream>>>(cur, nullptr, cv, wd, ddepth - 1, partial);
        P = 8;
    }

    int nt = B * odim;
    k_out<<<(nt + 255) / 256, 256, 0, stream>>>(partial, w_out, b_out, out, B, odim, P);
}

// Round 6
// 44.069 us; speedup vs baseline: 2.6859x; 1.2539x over previous
//
#include <hip/hip_runtime.h>
#include <hip/hip_fp16.h>
#include <math.h>

// ---------------------------------------------------------------------------
// ConvQCL — quanvolution + 16-qubit dense quantum circuit.
//
// Conv cells (9 qubits, REAL state): one wave per cell, 8 amps/lane in
//   registers; CNOT staircase == gray map -> shfl; RY = register/shfl_xor
//   butterflies. Zero barriers, zero LDS. Conv block 0 also bias-inits d_out.
//
// Dense pipeline (ddepth=2 fast path, generic ddepth>=1):
//   K_slab<INIT>:  psi0 gray-gathered (folds perm P0) + layer-0 RY on bits
//                  0..12 (wires 3..15), registers + 2 LDS transposes. write.
//   K_mid:         B0 high (wires 0..2) + perm P1 (3-bit gray gather +
//                  partner exchange tid^128) + B1 high.  read+write.
//   K_slab<MEAS>:  layer-1 RY on bits 0..12 + fused per-wire marginals +
//                  fused output GEMV via atomicAdd into d_out.  read.
// Intermediate state stored as __half2 (re,im) — f32 compute, fp16 storage.
// Half-angle closed forms replace asin/acos+sincos (exact):
//   cos(asin(y)/2) = sqrt((1+sqrt(1-y^2))/2), sin = copysign(sqrt((1-t)/2),y)
//   cos(acos(u)/2) = sqrt((1+u)/2),           sin = sqrt((1-u)/2)
// ---------------------------------------------------------------------------

__device__ __forceinline__ float2 cmul(float2 a, float2 b) {
    return make_float2(a.x * b.x - a.y * b.y, a.x * b.y + a.y * b.x);
}
__device__ __forceinline__ unsigned ginv13(unsigned x) {
    x ^= x >> 1; x ^= x >> 2; x ^= x >> 4; x ^= x >> 8;
    return x & 0x1FFFu;
}
__device__ __forceinline__ int sw(int i) { return i ^ ((i >> 5) & 31); }

__device__ __forceinline__ __half2 pack(float2 f) {
    return __floats2half2_rn(f.x, f.y);
}
__device__ __forceinline__ float2 unpack(__half2 h) {
    return __half22float2(h);
}

// s,c of asin(y)/2 — exact half-angle identity, 3 sqrts, no libm.
__device__ __forceinline__ void half_asin_sc(float y, float* s, float* c) {
    float t = sqrtf(fmaxf(0.f, 1.f - y * y));
    *c = sqrtf(0.5f * (1.f + t));
    *s = copysignf(sqrtf(fmaxf(0.f, 0.5f * (1.f - t))), y);
}

#define BFLY(A0, A1, C, S)                                        \
    {                                                             \
        float2 t0 = (A0), t1 = (A1);                              \
        (A0) = make_float2((C)*t0.x - (S)*t1.x, (C)*t0.y - (S)*t1.y); \
        (A1) = make_float2((S)*t0.x + (C)*t1.x, (S)*t0.y + (C)*t1.y); \
    }

// ---------------- K1: conv cells — one wave per cell, barrier-free ----------
__global__ void __launch_bounds__(256)
k_conv(const float* __restrict__ x, const float* __restrict__ wc,
       float* __restrict__ cv, int cdepth, int ncell,
       const float* __restrict__ b_out, float* __restrict__ out,
       int nout, int odim)
{
    const int gt   = blockIdx.x * blockDim.x + threadIdx.x;
    const int cell = gt >> 6;
    const int lane = gt & 63;

    // bias-init d_out (meas kernel atomicAdds later; stream order guarantees)
    if (blockIdx.x == 0) {
        for (int t = threadIdx.x; t < nout; t += 256) out[t] = b_out[t % odim];
    }
    if (cell >= ncell) return;
    const int b = cell >> 6, pos = cell & 63, r = pos >> 3, c = pos & 7;

    float c9[9], s9[9];
    #pragma unroll
    for (int w = 0; w < 9; ++w) {
        int kh = w / 3, kw = w % 3;
        int rr = r - 1 + kh, cc = c - 1 + kw;
        float y = 0.f;                               // padding -> angle 0
        if (rr >= 0 && rr < 8 && cc >= 0 && cc < 8)
            y = 2.f * x[(b * 8 + rr) * 8 + cc] - 1.f;
        half_asin_sc(y, &s9[w], &c9[w]);             // sin/cos(asin(y)/2)
    }

    float lprod = 1.f;
    #pragma unroll
    for (int w = 3; w < 9; ++w) {
        int bit = (lane >> (8 - w)) & 1;
        lprod *= bit ? s9[w] : c9[w];
    }
    float v[8];
    #pragma unroll
    for (int j = 0; j < 8; ++j) {
        float f = (((j >> 2) & 1) ? s9[0] : c9[0]) *
                  (((j >> 1) & 1) ? s9[1] : c9[1]) *
                  (((j >> 0) & 1) ? s9[2] : c9[2]);
        v[j] = f * lprod;
    }

    const int glane = (lane ^ (lane >> 1)) & 63;
    for (int k = 0; k < cdepth; ++k) {
        float nv[8];
        #pragma unroll
        for (int j = 0; j < 8; ++j) {
            const int sj = j ^ (j >> 1);
            nv[j] = __shfl(v[sj], glane ^ ((j & 1) << 5), 64);
        }
        #pragma unroll
        for (int j = 0; j < 8; ++j) v[j] = nv[j];

        #pragma unroll
        for (int w = 0; w < 3; ++w) {
            float s, cc2; sincosf(0.5f * wc[k * 9 + w], &s, &cc2);
            const int st = 1 << (2 - w);
            #pragma unroll
            for (int j = 0; j < 8; ++j)
                if (!(j & st)) {
                    float a0 = v[j], a1 = v[j | st];
                    v[j]      = cc2 * a0 - s * a1;
                    v[j | st] = s * a0 + cc2 * a1;
                }
        }
        #pragma unroll
        for (int w = 3; w < 9; ++w) {
            float s, cc2; sincosf(0.5f * wc[k * 9 + w], &s, &cc2);
            const int p = 8 - w;
            const float sgn = ((lane >> p) & 1) ? s : -s;
            #pragma unroll
            for (int j = 0; j < 8; ++j) {
                float part = __shfl_xor(v[j], 1 << p, 64);
                v[j] = cc2 * v[j] + sgn * part;
            }
        }
    }

    float pz = 0.f;
    #pragma unroll
    for (int j = 0; j < 8; ++j) pz += (j & 4) ? -v[j] * v[j] : v[j] * v[j];
    #pragma unroll
    for (int off = 32; off > 0; off >>= 1) pz += __shfl_xor(pz, off, 64);
    if (lane == 0) cv[cell] = pz;
}

// ---------------- K_slab: low-13-bit wires within an 8192-amp slab ----------
// grid: B*8 blocks (slab = cell*8 + h), 256 threads, 32 amps/thread.
template<bool INIT, bool MEASURE>
__global__ void __launch_bounds__(256)
k_slab(const __half2* __restrict__ in, __half2* __restrict__ outb,
       const float* __restrict__ cvbuf, const float* __restrict__ wd,
       int k, const float* __restrict__ w_out, float* __restrict__ out,
       int odim)
{
    __shared__ float2 tile[8192];   // 64 KB; aliased for tables / reduction
    __shared__ float bp[16];
    const int tid  = threadIdx.x;
    const int slab = blockIdx.x;
    const int cell = slab >> 3, h = slab & 7;
    const float* wdk = wd + k * 16;

    float cb[13], sb[13];           // bit p (0..12) -> wire 15-p
    #pragma unroll
    for (int p = 0; p < 13; ++p) sincosf(0.5f * wdk[15 - p], &sb[p], &cb[p]);

    float2 v[32];

    if (INIT) {
        float2* coef = tile;            // [16][2]
        float2* TH   = tile + 32;       // [256]
        float2* TL   = tile + 288;      // [256]
        if (tid < 16) {
            int pr = tid >> 2, pc = tid & 3;
            const float* base = cvbuf + cell * 64;
            float m0 = base[(2 * pr) * 8 + 2 * pc];
            float m1 = base[(2 * pr) * 8 + 2 * pc + 1];
            float m2 = base[(2 * pr + 1) * 8 + 2 * pc];
            float m3 = base[(2 * pr + 1) * 8 + 2 * pc + 1];
            float xv = fmaxf(fmaxf(m0, m1), fmaxf(m2, m3));
            xv = fminf(1.f, fmaxf(-1.f, xv));
            float sa, ca, sbb, cbb;
            half_asin_sc(xv, &sa, &ca);             // sin/cos(asin(xv)/2)
            float u = xv * xv;                       // sin/cos(acos(u)/2)
            cbb = sqrtf(0.5f * (1.f + u));
            sbb = sqrtf(fmaxf(0.f, 0.5f * (1.f - u)));
            coef[2 * tid + 0] = make_float2(cbb * ca, -sbb * ca);
            coef[2 * tid + 1] = make_float2(cbb * sa,  sbb * sa);
        }
        __syncthreads();
        {
            float2 ph = make_float2(1.f, 0.f), pl = make_float2(1.f, 0.f);
            #pragma unroll
            for (int i = 0; i < 8; ++i) {
                int bh = (tid >> (7 - i)) & 1;
                ph = cmul(ph, coef[2 * i + bh]);
                pl = cmul(pl, coef[2 * (8 + i) + bh]);
            }
            TH[tid] = ph; TL[tid] = pl;
        }
        __syncthreads();
        unsigned cbase = ((unsigned)h << 13) | ((unsigned)tid << 5);
        unsigned g  = cbase ^ (cbase >> 1);
        float2 th   = TH[(g >> 8) & 255];
        unsigned gb = g & 255;
        #pragma unroll
        for (int j = 0; j < 32; ++j) {
            unsigned gj = gb ^ (unsigned)(j ^ (j >> 1));   // gray5(j) fold
            v[j] = cmul(th, TL[gj]);
        }
        __syncthreads();   // tables dead; tile reusable
    } else {
        const uint4* g4 = (const uint4*)(in + (((size_t)slab << 13) + tid * 32));
        #pragma unroll
        for (int j = 0; j < 8; ++j) {
            uint4 q = g4[j];
            v[4 * j + 0] = unpack(*reinterpret_cast<__half2*>(&q.x));
            v[4 * j + 1] = unpack(*reinterpret_cast<__half2*>(&q.y));
            v[4 * j + 2] = unpack(*reinterpret_cast<__half2*>(&q.z));
            v[4 * j + 3] = unpack(*reinterpret_cast<__half2*>(&q.w));
        }
    }

    // bits 0..4 (wires 15..11), in-register
    #pragma unroll
    for (int b = 0; b < 5; ++b) {
        #pragma unroll
        for (int j = 0; j < 32; ++j)
            if (!(j & (1 << b))) BFLY(v[j], v[j | (1 << b)], cb[b], sb[b]);
    }

    // transpose A: register axis -> bits 5..9
    {
        int base = tid * 32;
        #pragma unroll
        for (int j = 0; j < 32; ++j) tile[sw(base + j)] = v[j];
    }
    __syncthreads();
    {
        int a = tid & 31, b3 = tid >> 5;
        #pragma unroll
        for (int j2 = 0; j2 < 32; ++j2)
            v[j2] = tile[sw(a | (j2 << 5) | (b3 << 10))];
    }
    __syncthreads();

    // bits 5..9 (wires 10..6)
    #pragma unroll
    for (int q = 0; q < 5; ++q) {
        #pragma unroll
        for (int j = 0; j < 32; ++j)
            if (!(j & (1 << q))) BFLY(v[j], v[j | (1 << q)], cb[5 + q], sb[5 + q]);
    }

    // transpose B: register axis -> bits {5,6} + {10,11,12}
    {
        int a = tid & 31, b3 = tid >> 5;
        #pragma unroll
        for (int j2 = 0; j2 < 32; ++j2)
            tile[sw(a | (j2 << 5) | (b3 << 10))] = v[j2];
    }
    __syncthreads();
    int a5 = tid & 31, d3 = tid >> 5;
    #pragma unroll
    for (int j3 = 0; j3 < 32; ++j3)
        v[j3] = tile[sw(a5 | ((j3 & 3) << 5) | (d3 << 7) | ((j3 >> 2) << 10))];

    // bits 10..12 (wires 5..3)
    #pragma unroll
    for (int r = 0; r < 3; ++r) {
        int st = 4 << r;
        #pragma unroll
        for (int j = 0; j < 32; ++j)
            if (!(j & st)) BFLY(v[j], v[j | st], cb[10 + r], sb[10 + r]);
    }

    if (!MEASURE) {
        __half2* gdst = outb + ((size_t)slab << 13);
        #pragma unroll
        for (int j3 = 0; j3 < 32; ++j3)
            gdst[a5 | ((j3 & 3) << 5) | (d3 << 7) | ((j3 >> 2) << 10)] = pack(v[j3]);
    } else {
        float tot = 0.f, m5 = 0.f, m6 = 0.f, m10 = 0.f, m11 = 0.f, m12 = 0.f;
        #pragma unroll
        for (int j3 = 0; j3 < 32; ++j3) {
            float p = v[j3].x * v[j3].x + v[j3].y * v[j3].y;
            tot += p;
            if (!(j3 & 1))  m5  += p;
            if (!(j3 & 2))  m6  += p;
            if (!(j3 & 4))  m10 += p;
            if (!(j3 & 8))  m11 += p;
            if (!(j3 & 16)) m12 += p;
        }
        float ws16[16];
        ws16[0]  = (h & 4) ? 0.f : tot;
        ws16[1]  = (h & 2) ? 0.f : tot;
        ws16[2]  = (h & 1) ? 0.f : tot;
        ws16[3]  = m12;
        ws16[4]  = m11;
        ws16[5]  = m10;
        ws16[6]  = (d3 & 4) ? 0.f : tot;
        ws16[7]  = (d3 & 2) ? 0.f : tot;
        ws16[8]  = (d3 & 1) ? 0.f : tot;
        ws16[9]  = m6;
        ws16[10] = m5;
        ws16[11] = (a5 & 16) ? 0.f : tot;
        ws16[12] = (a5 & 8)  ? 0.f : tot;
        ws16[13] = (a5 & 4)  ? 0.f : tot;
        ws16[14] = (a5 & 2)  ? 0.f : tot;
        ws16[15] = (a5 & 1)  ? 0.f : tot;

        __syncthreads();
        float* red = (float*)tile;       // [256][17]
        #pragma unroll
        for (int i = 0; i < 16; ++i) red[tid * 17 + i] = ws16[i];
        __syncthreads();
        int ii = tid & 15, s = tid >> 4;
        float acc = 0.f;
        #pragma unroll
        for (int r = 0; r < 16; ++r) acc += red[(s * 16 + r) * 17 + ii];
        __syncthreads();
        red[s * 17 + ii] = acc;
        __syncthreads();
        if (tid < 16) {
            float t2 = 0.f;
            #pragma unroll
            for (int s2 = 0; s2 < 16; ++s2) t2 += red[s2 * 17 + tid];
            bp[tid] = t2;                // block's 16 feature partials
        }
        __syncthreads();
        if (tid < odim) {                // fused GEMV: out[cell,o] += bp . w
            float acc2 = 0.f;
            #pragma unroll
            for (int i = 0; i < 16; ++i) acc2 += bp[i] * w_out[i * odim + tid];
            atomicAdd(&out[cell * odim + tid], acc2);
        }
    }
}

// ---------------- K_mid: high-3 wires + perm (+ next layer's high-3) --------
template<bool MEASURE>
__global__ void __launch_bounds__(256)
k_mid(const __half2* __restrict__ in, __half2* __restrict__ outb,
      const float* __restrict__ wd, int k, int prev_high,
      float* __restrict__ partial)
{
    __shared__ float2 ex[256][5];
    __shared__ float red[256][17];
    const int tid  = threadIdx.x;
    const int cell = blockIdx.x >> 5, chunk = blockIdx.x & 31;
    const int b12 = tid >> 7, l7 = tid & 127;
    const unsigned L = ((unsigned)b12 << 12) | ((unsigned)chunk << 7) | (unsigned)l7;
    const __half2* gi = in + ((size_t)cell << 16);

    float2 v[8];
    #pragma unroll
    for (int hh = 0; hh < 8; ++hh) v[hh] = unpack(gi[((size_t)hh << 13) | L]);

    if (prev_high) {
        #pragma unroll
        for (int w = 0; w < 3; ++w) {
            float s, c; sincosf(0.5f * wd[(k - 1) * 16 + w], &s, &c);
            int st = 1 << (2 - w);
            #pragma unroll
            for (int hh = 0; hh < 8; ++hh)
                if (!(hh & st)) BFLY(v[hh], v[hh | st], c, s);
        }
    }

    if (MEASURE) {
        float p[8], tot = 0.f;
        #pragma unroll
        for (int hh = 0; hh < 8; ++hh) {
            p[hh] = v[hh].x * v[hh].x + v[hh].y * v[hh].y;
            tot += p[hh];
        }
        float ws16[16];
        ws16[0] = p[0] + p[1] + p[2] + p[3];
        ws16[1] = p[0] + p[1] + p[4] + p[5];
        ws16[2] = p[0] + p[2] + p[4] + p[6];
        #pragma unroll
        for (int w = 3; w < 16; ++w)
            ws16[w] = ((L >> (15 - w)) & 1) ? 0.f : tot;
        #pragma unroll
        for (int i = 0; i < 16; ++i) red[tid][i] = ws16[i];
        __syncthreads();
        int ii = tid & 15, s = tid >> 4;
        float acc = 0.f;
        #pragma unroll
        for (int r = 0; r < 16; ++r) acc += red[s * 16 + r][ii];
        __syncthreads();
        red[s][ii] = acc;
        __syncthreads();
        if (tid < 16) {
            float t2 = 0.f;
            #pragma unroll
            for (int s2 = 0; s2 < 16; ++s2) t2 += red[s2][tid];
            partial[(size_t)blockIdx.x * 16 + tid] = t2;
        }
        return;
    }

    // P_k high bits: w8[h'] = v[gray3(h')]
    float2 w8[8];
    w8[0] = v[0]; w8[1] = v[1]; w8[2] = v[3]; w8[3] = v[2];
    w8[4] = v[6]; w8[5] = v[7]; w8[6] = v[5]; w8[7] = v[4];

    ex[tid ^ 128][0] = w8[1]; ex[tid ^ 128][1] = w8[3];
    ex[tid ^ 128][2] = w8[5]; ex[tid ^ 128][3] = w8[7];
    __syncthreads();
    w8[1] = ex[tid][0]; w8[3] = ex[tid][1];
    w8[5] = ex[tid][2]; w8[7] = ex[tid][3];

    #pragma unroll
    for (int w = 0; w < 3; ++w) {
        float s, c; sincosf(0.5f * wd[k * 16 + w], &s, &c);
        int st = 1 << (2 - w);
        #pragma unroll
        for (int hh = 0; hh < 8; ++hh)
            if (!(hh & st)) BFLY(w8[hh], w8[hh | st], c, s);
    }

    unsigned Lp = ginv13(L);
    __half2* go = outb + ((size_t)cell << 16);
    #pragma unroll
    for (int hh = 0; hh < 8; ++hh) go[((size_t)hh << 13) | Lp] = pack(w8[hh]);
}

// ---------------- K_out (generic ddepth==1 fallback only) -------------------
__global__ void k_out(const float* __restrict__ partial,
                      const float* __restrict__ w_out,
                      const float* __restrict__ b_out,
                      float* __restrict__ out, int B, int odim, int P)
{
    int t = blockIdx.x * blockDim.x + threadIdx.x;
    if (t >= B * odim) return;
    int b = t / odim, o = t % odim;
    float acc = b_out[o];
    for (int i = 0; i < 16; ++i) {
        float f = 0.f;
        const float* pp = partial + (size_t)(b * P) * 16 + i;
        for (int s = 0; s < P; ++s) f += pp[s * 16];
        acc += f * w_out[i * odim + o];
    }
    out[t] = acc;
}

// ---------------------------------------------------------------------------
extern "C" void kernel_launch(void* const* d_in, const int* in_sizes, int n_in,
                              void* d_out, int out_size, void* d_ws, size_t ws_size,
                              hipStream_t stream)
{
    (void)n_in; (void)out_size; (void)ws_size;
    const float* x     = (const float*)d_in[0];
    const float* wc    = (const float*)d_in[1];
    const float* wd    = (const float*)d_in[2];
    const float* w_out = (const float*)d_in[3];
    const float* b_out = (const float*)d_in[4];
    float* out = (float*)d_out;

    const int B      = in_sizes[0] / 64;
    const int cdepth = in_sizes[1] / 9;
    const int ddepth = in_sizes[2] / 16;
    const int odim   = in_sizes[3] / 16;

    char* ws = (char*)d_ws;
    size_t off = 0;
    float* cv = (float*)(ws + off);      off += (size_t)B * 64 * sizeof(float);
    off = (off + 255) & ~(size_t)255;
    float* partial = (float*)(ws + off); off += (size_t)B * 32 * 16 * sizeof(float);
    off = (off + 255) & ~(size_t)255;
    __half2* buf0 = (__half2*)(ws + off); off += (size_t)B * 65536 * sizeof(__half2);
    __half2* buf1 = (__half2*)(ws + off);

    const int ncell = B * 64;
    k_conv<<<(ncell * 64 + 255) / 256, 256, 0, stream>>>(
        x, wc, cv, cdepth, ncell, b_out, out, B * odim, odim);

    // K1: psi0 (P0 folded) + B0 low wires
    k_slab<true, false><<<B * 8, 256, 0, stream>>>(
        nullptr, buf0, cv, wd, 0, nullptr, nullptr, odim);

    if (ddepth == 1) {
        k_mid<true><<<B * 32, 256, 0, stream>>>(buf0, nullptr, wd, 1, 1, partial);
        int nt = B * odim;
        k_out<<<(nt + 255) / 256, 256, 0, stream>>>(partial, w_out, b_out, out,
                                                    B, odim, 32);
    } else {
        k_mid<false><<<B * 32, 256, 0, stream>>>(buf0, buf1, wd, 1, 1, nullptr);
        __half2* cur = buf1; __half2* oth = buf0;
        for (int k = 2; k <= ddepth - 1; ++k) {
            k_slab<false, false><<<B * 8, 256, 0, stream>>>(
                cur, oth, cv, wd, k - 1, nullptr, nullptr, odim);
            { __half2* t = cur; cur = oth; oth = t; }
            k_mid<false><<<B * 32, 256, 0, stream>>>(cur, oth, wd, k, 0, nullptr);
            { __half2* t = cur; cur = oth; oth = t; }
        }
        // terminal: measure + fused GEMV into d_out (bias written by k_conv)
        k_slab<false, true><<<B * 8, 256, 0, stream>>>(
            cur, nullptr, cv, wd, ddepth - 1, w_out, out, odim);
    }
}